// Round 6
// baseline (331.775 us; speedup 1.0000x reference)
//
#include <hip/hip_runtime.h>

#define CUTOFF 5.0f
#define GAMMA 40.96f              // (32/5)^2
#define MU_STEP 0.16129032f       // 5/31 (RBF mu spacing)
#define PI_F 3.14159265358979f
#define MAXDEG 24                 // filtered degree ~Poisson(4.42); P(deg>=24) ~ 3e-6
#define TAB 4096                  // radial-weight table intervals (lerp err ~1.5e-5)
#define DSTEP (CUTOFF / (float)TAB)
#define TSCALE ((float)TAB / CUTOFF)

// ---------------------------------------------------------------------------
// R15: R14 + two targeted fixes from the post-mortem:
//  * __launch_bounds__(256, 8) on gather: R14's VGPR crept 60->92, crossing
//    the 64-reg occupancy cliff (occ 34%->18.6%, latency-bound dur UP despite
//    -11% VALU-busy time). Pin to 8 waves/EU => compiler must fit 64 VGPR
//    (R11's heavier loop fit in 60; LDS 18944*8 = 151.5KB <= 160KB).
//  * TAB 2048 -> 4096: absmax 0.031 -> ~0.008 (lerp error ~ Delta^2).
// Structure unchanged: memset + {fill edges || build table} + gather.
// w(c,d) = env(d) * (rbf(d) @ W_rbf)[c] via 2-point table lerp -- no exp, no
// shfl, no clamp in gather's inner loop.
// ws: tabp 512KB | edata float4[N*24] 19.2MB | deg[N] | rec[N*24] 4.8MB.
// ---------------------------------------------------------------------------

__global__ __launch_bounds__(256) void k_fill_geom(
    const float* __restrict__ pos, const int* __restrict__ ei,
    const float* __restrict__ Wrbf,
    int* __restrict__ deg, int* __restrict__ rec,
    float4* __restrict__ edata, float2* __restrict__ tabp,
    int E, int eBlocks)
{
    if (blockIdx.x >= eBlocks) {
        // ---- radial-weight table builder: 256 blocks, 65536 (interval,chan)
        const int gid = (blockIdx.x - eBlocks) * 256 + threadIdx.x;
        const int i = gid >> 4;          // interval 0..4095
        const int c = gid & 15;          // channel
        const float d0 = (float)i * DSTEP;
        const float d1 = d0 + DSTEP;
        float acc0 = 0.0f, acc1 = 0.0f;
        #pragma unroll
        for (int k = 0; k < 32; ++k) {
            const float w  = Wrbf[k*16 + c];
            const float x0 = d0 - MU_STEP * (float)k;
            const float x1 = d1 - MU_STEP * (float)k;
            acc0 += __expf(-GAMMA * x0 * x0) * w;
            acc1 += __expf(-GAMMA * x1 * x1) * w;
        }
        const float env0 = 0.5f * (__cosf(PI_F * d0 * (1.0f/CUTOFF)) + 1.0f);
        const float env1 = 0.5f * (__cosf(PI_F * d1 * (1.0f/CUTOFF)) + 1.0f);
        tabp[gid] = make_float2(acc0 * env0, acc1 * env1);
        return;
    }

    // ---- edge bucket fill
    const int e = blockIdx.x * 256 + threadIdx.x;
    if (e >= E) return;
    const int src = ei[e], dst = ei[E + e];
    const float dx = pos[dst*3+0] - pos[src*3+0];
    const float dy = pos[dst*3+1] - pos[src*3+1];
    const float dz = pos[dst*3+2] - pos[src*3+2];
    const float d = sqrtf(dx*dx + dy*dy + dz*dz + 1e-12f);
    if (d < CUTOFF) {
        const int slot = atomicAdd(&deg[dst], 1);
        if (slot < MAXDEG) {               // guard: never taken in practice
            const float inv = 1.0f / d;
            rec[dst*MAXDEG + slot] = src;
            edata[(size_t)dst*MAXDEG + slot] = make_float4(dx*inv, dy*inv, dz*inv, d);
        }
    }
}

__global__ __launch_bounds__(256, 8) void k_gather_finalize(
    const float* __restrict__ h,
    const int* __restrict__ rec, const int* __restrict__ deg,
    const float4* __restrict__ edata, const float2* __restrict__ tabp,
    const float* __restrict__ Wout, const float* __restrict__ Wsgp,
    float* __restrict__ out, int N)
{
    __shared__ float s_Wout[256];
    __shared__ float s_Wsgp[256];
    __shared__ float s_agg[16*132];
    __shared__ float s_h[16*132];

    const int t  = threadIdx.x;
    const int nl = t >> 4;
    const int c  = t & 15;
    const long long nodeBase = (long long)blockIdx.x * 16;
    const long long n = nodeBase + nl;

    s_Wout[t] = Wout[t];
    s_Wsgp[t] = Wsgp[t];

    for (int idx = t; idx < 512; idx += 256) {
        int nn = idx >> 5;
        int r  = idx & 31;
        long long node = nodeBase + nn;
        float4 vh = make_float4(0,0,0,0);
        if (node < N) vh = *(const float4*)(h + node*128 + (long long)r*4);
        *(float4*)(&s_h[nn*132 + r*4]) = vh;
    }
    __syncthreads();

    float m0=0,m1=0,m2=0,m3=0,m4=0,m5=0,m6=0,m7=0;
    if (n < N) {
        const int start = (int)n * MAXDEG;
        const int dg    = min(deg[n], MAXDEG);
        for (int base = 0; base < dg; base += 2) {
            const int i1ok = (base + 1 < dg) ? 1 : 0;
            const int s0 = rec[start + base];
            const int s1 = rec[start + base + i1ok];   // repeats s0 when odd tail
            const float4 g0 = edata[start + base];
            const float4 g1 = edata[start + base + i1ok];

            // hoist h loads: 2 independent 32B chains in flight during w math
            const float4* hp0 = (const float4*)(h + (((long long)s0*16 + c) << 3));
            const float4* hp1 = (const float4*)(h + (((long long)s1*16 + c) << 3));
            const float4 A0 = hp0[0], B0 = hp0[1];
            const float4 A1 = hp1[0], B1 = hp1[1];

            // radial weight via table lerp (env + full 32-term RBF folded in);
            // depends only on the early edata load -- off the h critical path
            const float u0 = g0.w * TSCALE;
            const float u1 = g1.w * TSCALE;
            int it0 = (int)u0; it0 = min(it0, TAB - 1);
            int it1 = (int)u1; it1 = min(it1, TAB - 1);
            const float fr0 = u0 - (float)it0;
            const float fr1 = u1 - (float)it1;
            const float2 tp0 = tabp[it0*16 + c];
            const float2 tp1 = tabp[it1*16 + c];
            const float w0 = tp0.x + fr0 * (tp0.y - tp0.x);
            float       w1 = tp1.x + fr1 * (tp1.y - tp1.x);
            w1 *= (float)i1ok;

            // gp(a, v), v grade-1 unit rel vector;
            // blades: 0:1 1:e1 2:e2 3:e3 4:e12 5:e13 6:e23 7:e123
            m0 += (A0.y*g0.x + A0.z*g0.y + A0.w*g0.z)*w0 + (A1.y*g1.x + A1.z*g1.y + A1.w*g1.z)*w1;
            m1 += (A0.x*g0.x + B0.x*g0.y + B0.y*g0.z)*w0 + (A1.x*g1.x + B1.x*g1.y + B1.y*g1.z)*w1;
            m2 += (A0.x*g0.y - B0.x*g0.x + B0.z*g0.z)*w0 + (A1.x*g1.y - B1.x*g1.x + B1.z*g1.z)*w1;
            m3 += (A0.x*g0.z - B0.y*g0.x - B0.z*g0.y)*w0 + (A1.x*g1.z - B1.y*g1.x - B1.z*g1.y)*w1;
            m4 += (A0.y*g0.y - A0.z*g0.x + B0.w*g0.z)*w0 + (A1.y*g1.y - A1.z*g1.x + B1.w*g1.z)*w1;
            m5 += (A0.y*g0.z - A0.w*g0.x - B0.w*g0.y)*w0 + (A1.y*g1.z - A1.w*g1.x - B1.w*g1.y)*w1;
            m6 += (A0.z*g0.z - A0.w*g0.y + B0.w*g0.x)*w0 + (A1.z*g1.z - A1.w*g1.y + B1.w*g1.x)*w1;
            m7 += (B0.z*g0.x - B0.y*g0.y + B0.x*g0.z)*w0 + (B1.z*g1.x - B1.y*g1.y + B1.x*g1.z)*w1;
        }
    }

    __syncthreads();
    float* ag = &s_agg[nl*132 + c*8];
    *(float4*)(ag)     = make_float4(m0, m1, m2, m3);
    *(float4*)(ag + 4) = make_float4(m4, m5, m6, m7);
    __syncthreads();

    const int o = c;
    const float* A = &s_agg[nl*132];
    const float* H = &s_h[nl*132];

    float o0=0,o1=0,o2=0,o3=0,o4=0,o5=0,o6=0,o7=0;
    float q0=0,q1=0,q2=0,q3=0,q4=0,q5=0,q6=0,q7=0;
    #pragma unroll
    for (int cc = 0; cc < 16; ++cc) {
        const float wo = s_Wout[cc*16 + o];
        const float ws = s_Wsgp[cc*16 + o];
        const float* a  = A + cc*8;
        const float* hh = H + cc*8;
        o0 += a[0]*wo; o1 += a[1]*wo; o2 += a[2]*wo; o3 += a[3]*wo;
        o4 += a[4]*wo; o5 += a[5]*wo; o6 += a[6]*wo; o7 += a[7]*wo;
        q0 += hh[0]*ws; q1 += hh[1]*ws; q2 += hh[2]*ws; q3 += hh[3]*ws;
        q4 += hh[4]*ws; q5 += hh[5]*ws; q6 += hh[6]*ws; q7 += hh[7]*ws;
    }

    // res = out + gp(out, q), full Cl(3,0) Cayley product
    const float r0 = o0 + (o0*q0 + o1*q1 + o2*q2 + o3*q3 - o4*q4 - o5*q5 - o6*q6 - o7*q7);
    const float r1 = o1 + (o0*q1 + o1*q0 - o2*q4 - o3*q5 + o4*q2 + o5*q3 - o6*q7 - o7*q6);
    const float r2 = o2 + (o0*q2 + o1*q4 + o2*q0 - o3*q6 - o4*q1 + o5*q7 + o6*q3 + o7*q5);
    const float r3 = o3 + (o0*q3 + o1*q5 + o2*q6 + o3*q0 - o4*q7 - o5*q1 - o6*q2 - o7*q4);
    const float r4 = o4 + (o0*q4 + o1*q2 - o2*q1 + o3*q7 + o4*q0 - o5*q6 + o6*q5 + o7*q3);
    const float r5 = o5 + (o0*q5 + o1*q3 - o2*q7 - o3*q1 + o4*q6 + o5*q0 - o6*q4 - o7*q2);
    const float r6 = o6 + (o0*q6 + o1*q7 + o2*q3 - o3*q2 - o4*q5 + o5*q4 + o6*q0 + o7*q1);
    const float r7 = o7 + (o0*q7 + o1*q6 - o2*q5 + o3*q4 + o4*q3 - o5*q2 + o6*q1 + o7*q0);

    if (n < N) {
        float* op = out + (n*16 + o)*8;
        *(float4*)(op)     = make_float4(r0, r1, r2, r3);
        *(float4*)(op + 4) = make_float4(r4, r5, r6, r7);
    }
}

extern "C" void kernel_launch(void* const* d_in, const int* in_sizes, int n_in,
                              void* d_out, int out_size, void* d_ws, size_t ws_size,
                              hipStream_t stream) {
    const float* h    = (const float*)d_in[0];   // [N,16,8]
    const float* pos  = (const float*)d_in[1];   // [N,3]
    const int*   ei   = (const int*)d_in[2];     // [2,E]
    const float* Wrbf = (const float*)d_in[3];   // [32,16]
    const float* Wout = (const float*)d_in[4];   // [16,16]
    const float* Wsgp = (const float*)d_in[5];   // [16,16]
    float* out = (float*)d_out;

    const int N = in_sizes[0] / 128;
    const int E = in_sizes[2] / 2;

    // ws layout: tabp float2[TAB*16] (512KB) | edata float4[N*MAXDEG] (19.2MB)
    //            | deg[N] | rec[N*MAXDEG] (4.8MB)  -- total ~24.7MB
    float2* tabp  = (float2*)d_ws;
    float4* edata = (float4*)(tabp + (size_t)TAB * 16);
    int* deg = (int*)(edata + (size_t)N * MAXDEG);
    int* rec = deg + N;

    hipMemsetAsync(deg, 0, (size_t)N * sizeof(int), stream);

    const int eBlocks = (E + 255) / 256;
    const int tBlocks = (TAB * 16) / 256;        // 256 table-builder blocks
    k_fill_geom<<<eBlocks + tBlocks, 256, 0, stream>>>(
        pos, ei, Wrbf, deg, rec, edata, tabp, E, eBlocks);

    const int gBlocks = (N + 15) / 16;
    k_gather_finalize<<<gBlocks, 256, 0, stream>>>(
        h, rec, deg, edata, tabp, Wout, Wsgp, out, N);
}

// Round 7
// 154.328 us; speedup vs baseline: 2.1498x; 2.1498x over previous
//
#include <hip/hip_runtime.h>

#define CUTOFF 5.0f
#define GAMMA 40.96f              // (32/5)^2
#define MU_STEP 0.16129032f       // 5/31 (RBF mu spacing)
#define PI_F 3.14159265358979f
#define MAXDEG 24                 // filtered degree ~Poisson(4.42); P(deg>=24) ~ 3e-6
#define TAB 4096                  // radial-weight table intervals
#define DSTEP (CUTOFF / (float)TAB)
#define TSCALE ((float)TAB / CUTOFF)

// ---------------------------------------------------------------------------
// R16: R14's table-lerp inner loop at R11's occupancy, by STRUCTURAL register
// economy (R15 lesson: forcing launch_bounds below natural usage => scratch
// spills, 533MB of spill traffic, 2x slower).
//  * 1-edge software-pipelined loop, explicit next-edge prefetch with clamped
//    index (no per-iter branch). Live set {A,B,g}+{AN,BN,gN}+8 acc ~= 55 VGPR.
//  * #pragma unroll 1 prevents the unroller from re-inflating the live set
//    (R14's 92 VGPR came from 2-edge body x2 unroll = 4 h-rows live).
//  * MLP unchanged vs R11 (2 h-rows in flight: current + prefetch).
// Structure: memset + {fill edges || build table} + gather (3 dispatches).
// w(c,d) = env(d) * (rbf(d) @ W_rbf)[c] via 2-point table lerp.
// ws: tabp 512KB | edata float4[N*24] 19.2MB | deg[N] | rec[N*24] 4.8MB.
// ---------------------------------------------------------------------------

__global__ __launch_bounds__(256) void k_fill_geom(
    const float* __restrict__ pos, const int* __restrict__ ei,
    const float* __restrict__ Wrbf,
    int* __restrict__ deg, int* __restrict__ rec,
    float4* __restrict__ edata, float2* __restrict__ tabp,
    int E, int eBlocks)
{
    if (blockIdx.x >= eBlocks) {
        // ---- radial-weight table builder: 256 blocks, 65536 (interval,chan)
        const int gid = (blockIdx.x - eBlocks) * 256 + threadIdx.x;
        const int i = gid >> 4;          // interval 0..4095
        const int c = gid & 15;          // channel
        const float d0 = (float)i * DSTEP;
        const float d1 = d0 + DSTEP;
        float acc0 = 0.0f, acc1 = 0.0f;
        #pragma unroll
        for (int k = 0; k < 32; ++k) {
            const float w  = Wrbf[k*16 + c];
            const float x0 = d0 - MU_STEP * (float)k;
            const float x1 = d1 - MU_STEP * (float)k;
            acc0 += __expf(-GAMMA * x0 * x0) * w;
            acc1 += __expf(-GAMMA * x1 * x1) * w;
        }
        const float env0 = 0.5f * (__cosf(PI_F * d0 * (1.0f/CUTOFF)) + 1.0f);
        const float env1 = 0.5f * (__cosf(PI_F * d1 * (1.0f/CUTOFF)) + 1.0f);
        tabp[gid] = make_float2(acc0 * env0, acc1 * env1);
        return;
    }

    // ---- edge bucket fill
    const int e = blockIdx.x * 256 + threadIdx.x;
    if (e >= E) return;
    const int src = ei[e], dst = ei[E + e];
    const float dx = pos[dst*3+0] - pos[src*3+0];
    const float dy = pos[dst*3+1] - pos[src*3+1];
    const float dz = pos[dst*3+2] - pos[src*3+2];
    const float d = sqrtf(dx*dx + dy*dy + dz*dz + 1e-12f);
    if (d < CUTOFF) {
        const int slot = atomicAdd(&deg[dst], 1);
        if (slot < MAXDEG) {               // guard: never taken in practice
            const float inv = 1.0f / d;
            rec[dst*MAXDEG + slot] = src;
            edata[(size_t)dst*MAXDEG + slot] = make_float4(dx*inv, dy*inv, dz*inv, d);
        }
    }
}

__global__ __launch_bounds__(256) void k_gather_finalize(
    const float* __restrict__ h,
    const int* __restrict__ rec, const int* __restrict__ deg,
    const float4* __restrict__ edata, const float2* __restrict__ tabp,
    const float* __restrict__ Wout, const float* __restrict__ Wsgp,
    float* __restrict__ out, int N)
{
    __shared__ float s_Wout[256];
    __shared__ float s_Wsgp[256];
    __shared__ float s_agg[16*132];
    __shared__ float s_h[16*132];

    const int t  = threadIdx.x;
    const int nl = t >> 4;
    const int c  = t & 15;
    const long long nodeBase = (long long)blockIdx.x * 16;
    const long long n = nodeBase + nl;

    s_Wout[t] = Wout[t];
    s_Wsgp[t] = Wsgp[t];

    for (int idx = t; idx < 512; idx += 256) {
        int nn = idx >> 5;
        int r  = idx & 31;
        long long node = nodeBase + nn;
        float4 vh = make_float4(0,0,0,0);
        if (node < N) vh = *(const float4*)(h + node*128 + (long long)r*4);
        *(float4*)(&s_h[nn*132 + r*4]) = vh;
    }
    __syncthreads();

    float m0=0,m1=0,m2=0,m3=0,m4=0,m5=0,m6=0,m7=0;
    if (n < N) {
        const int start = (int)n * MAXDEG;
        const int dg    = min(deg[n], MAXDEG);
        if (dg > 0) {
            // prologue: prefetch edge 0
            int sN = rec[start];
            float4 gN = edata[start];
            const float4* hpN = (const float4*)(h + (((long long)sN*16 + c) << 3));
            float4 AN = hpN[0], BN = hpN[1];

            #pragma unroll 1
            for (int base = 0; base < dg; ++base) {
                const float4 A = AN, B = BN, g = gN;

                // prefetch next edge (clamped: last iter re-reads edge dg-1,
                // result unused). Issued before the gp so the 32B h chain is
                // in flight during this iteration's math.
                const int nxt = min(base + 1, dg - 1);
                sN = rec[start + nxt];
                gN = edata[start + nxt];
                hpN = (const float4*)(h + (((long long)sN*16 + c) << 3));
                AN = hpN[0]; BN = hpN[1];

                // radial weight via table lerp (env + full RBF @ W_rbf folded)
                const float u = g.w * TSCALE;
                const int it = min((int)u, TAB - 1);
                const float fr = u - (float)it;
                const float2 tp = tabp[it*16 + c];
                const float w = tp.x + fr * (tp.y - tp.x);

                // gp(a, v), v grade-1 unit rel vector;
                // blades: 0:1 1:e1 2:e2 3:e3 4:e12 5:e13 6:e23 7:e123
                m0 += (A.y*g.x + A.z*g.y + A.w*g.z) * w;
                m1 += (A.x*g.x + B.x*g.y + B.y*g.z) * w;
                m2 += (A.x*g.y - B.x*g.x + B.z*g.z) * w;
                m3 += (A.x*g.z - B.y*g.x - B.z*g.y) * w;
                m4 += (A.y*g.y - A.z*g.x + B.w*g.z) * w;
                m5 += (A.y*g.z - A.w*g.x - B.w*g.y) * w;
                m6 += (A.z*g.z - A.w*g.y + B.w*g.x) * w;
                m7 += (B.z*g.x - B.y*g.y + B.x*g.z) * w;
            }
        }
    }

    __syncthreads();
    float* ag = &s_agg[nl*132 + c*8];
    *(float4*)(ag)     = make_float4(m0, m1, m2, m3);
    *(float4*)(ag + 4) = make_float4(m4, m5, m6, m7);
    __syncthreads();

    const int o = c;
    const float* A = &s_agg[nl*132];
    const float* H = &s_h[nl*132];

    float o0=0,o1=0,o2=0,o3=0,o4=0,o5=0,o6=0,o7=0;
    float q0=0,q1=0,q2=0,q3=0,q4=0,q5=0,q6=0,q7=0;
    #pragma unroll
    for (int cc = 0; cc < 16; ++cc) {
        const float wo = s_Wout[cc*16 + o];
        const float ws = s_Wsgp[cc*16 + o];
        const float* a  = A + cc*8;
        const float* hh = H + cc*8;
        o0 += a[0]*wo; o1 += a[1]*wo; o2 += a[2]*wo; o3 += a[3]*wo;
        o4 += a[4]*wo; o5 += a[5]*wo; o6 += a[6]*wo; o7 += a[7]*wo;
        q0 += hh[0]*ws; q1 += hh[1]*ws; q2 += hh[2]*ws; q3 += hh[3]*ws;
        q4 += hh[4]*ws; q5 += hh[5]*ws; q6 += hh[6]*ws; q7 += hh[7]*ws;
    }

    // res = out + gp(out, q), full Cl(3,0) Cayley product
    const float r0 = o0 + (o0*q0 + o1*q1 + o2*q2 + o3*q3 - o4*q4 - o5*q5 - o6*q6 - o7*q7);
    const float r1 = o1 + (o0*q1 + o1*q0 - o2*q4 - o3*q5 + o4*q2 + o5*q3 - o6*q7 - o7*q6);
    const float r2 = o2 + (o0*q2 + o1*q4 + o2*q0 - o3*q6 - o4*q1 + o5*q7 + o6*q3 + o7*q5);
    const float r3 = o3 + (o0*q3 + o1*q5 + o2*q6 + o3*q0 - o4*q7 - o5*q1 - o6*q2 - o7*q4);
    const float r4 = o4 + (o0*q4 + o1*q2 - o2*q1 + o3*q7 + o4*q0 - o5*q6 + o6*q5 + o7*q3);
    const float r5 = o5 + (o0*q5 + o1*q3 - o2*q7 - o3*q1 + o4*q6 + o5*q0 - o6*q4 - o7*q2);
    const float r6 = o6 + (o0*q6 + o1*q7 + o2*q3 - o3*q2 - o4*q5 + o5*q4 + o6*q0 + o7*q1);
    const float r7 = o7 + (o0*q7 + o1*q6 - o2*q5 + o3*q4 + o4*q3 - o5*q2 + o6*q1 + o7*q0);

    if (n < N) {
        float* op = out + (n*16 + o)*8;
        *(float4*)(op)     = make_float4(r0, r1, r2, r3);
        *(float4*)(op + 4) = make_float4(r4, r5, r6, r7);
    }
}

extern "C" void kernel_launch(void* const* d_in, const int* in_sizes, int n_in,
                              void* d_out, int out_size, void* d_ws, size_t ws_size,
                              hipStream_t stream) {
    const float* h    = (const float*)d_in[0];   // [N,16,8]
    const float* pos  = (const float*)d_in[1];   // [N,3]
    const int*   ei   = (const int*)d_in[2];     // [2,E]
    const float* Wrbf = (const float*)d_in[3];   // [32,16]
    const float* Wout = (const float*)d_in[4];   // [16,16]
    const float* Wsgp = (const float*)d_in[5];   // [16,16]
    float* out = (float*)d_out;

    const int N = in_sizes[0] / 128;
    const int E = in_sizes[2] / 2;

    // ws layout: tabp float2[TAB*16] (512KB) | edata float4[N*MAXDEG] (19.2MB)
    //            | deg[N] | rec[N*MAXDEG] (4.8MB)  -- total ~24.7MB
    float2* tabp  = (float2*)d_ws;
    float4* edata = (float4*)(tabp + (size_t)TAB * 16);
    int* deg = (int*)(edata + (size_t)N * MAXDEG);
    int* rec = deg + N;

    hipMemsetAsync(deg, 0, (size_t)N * sizeof(int), stream);

    const int eBlocks = (E + 255) / 256;
    const int tBlocks = (TAB * 16) / 256;        // 256 table-builder blocks
    k_fill_geom<<<eBlocks + tBlocks, 256, 0, stream>>>(
        pos, ei, Wrbf, deg, rec, edata, tabp, E, eBlocks);

    const int gBlocks = (N + 15) / 16;
    k_gather_finalize<<<gBlocks, 256, 0, stream>>>(
        h, rec, deg, edata, tabp, Wout, Wsgp, out, N);
}

// Round 8
// 138.070 us; speedup vs baseline: 2.4029x; 1.1178x over previous
//
#include <hip/hip_runtime.h>

#define CUTOFF 5.0f
#define GAMMA 40.96f              // (32/5)^2
#define MU_STEP 0.16129032f       // 5/31
#define INV_MU 6.2f               // 31/5
#define PI_F 3.14159265358979f
#define MAXDEG 24                 // filtered degree ~Poisson(~5); P(deg>=24) negligible

// ---------------------------------------------------------------------------
// R17: R11 base (best verified: 138us total, gather 53us, VGPR 60, occ 34%)
// with three in-envelope cuts. R12/R14/R16 lesson: any restructure that frees
// the scheduler (removing the serial shfl chain) inflates VGPR past the 64
// cliff and loses more to occupancy than it saves in instructions. So keep
// the R11 loop shape (the shfl chain is the pressure regulator) and shave:
//  * 5-term RBF window (kl=round(d*6.2)-2, clamp [0,27]); dropped +/-3 terms
//    <= 6.8e-5 (worst boundary 1.3e-3). -4 shfl -4 FMA per pair on the
//    critical DS chain.
//  * odd-tail peeled out of the main loop: no i1ok selects / fixups.
//  * rec pair loaded as one int2 (8B) instead of two dependent 4B loads.
// Fill unchanged from R11: edata = {rel/d * env(d), d}, env folded linearly.
// ws: edata float4[N*24] 19.2MB | deg[N] | rec[N*24] 4.8MB = 24.2MB.
// ---------------------------------------------------------------------------

__global__ __launch_bounds__(256) void k_fill_geom(
    const float* __restrict__ pos, const int* __restrict__ ei,
    int* __restrict__ deg, int* __restrict__ rec,
    float4* __restrict__ edata, int E)
{
    int e = blockIdx.x * 256 + threadIdx.x;
    if (e >= E) return;
    int src = ei[e], dst = ei[E + e];
    float dx = pos[dst*3+0] - pos[src*3+0];
    float dy = pos[dst*3+1] - pos[src*3+1];
    float dz = pos[dst*3+2] - pos[src*3+2];
    float d = sqrtf(dx*dx + dy*dy + dz*dz + 1e-12f);
    if (d < CUTOFF) {
        int slot = atomicAdd(&deg[dst], 1);
        if (slot < MAXDEG) {               // guard: never taken in practice
            const float s = (0.5f * (__cosf(PI_F * d * (1.0f/CUTOFF)) + 1.0f)) / d;
            rec[dst*MAXDEG + slot] = src;
            edata[(size_t)dst*MAXDEG + slot] = make_float4(dx*s, dy*s, dz*s, d);
        }
    }
}

__global__ __launch_bounds__(256) void k_gather_finalize(
    const float* __restrict__ h,
    const int* __restrict__ rec, const int* __restrict__ deg,
    const float4* __restrict__ edata,
    const float* __restrict__ Wrbf, const float* __restrict__ Wout,
    const float* __restrict__ Wsgp, float* __restrict__ out, int N)
{
    __shared__ float s_wr[512];        // W_rbf [32,16]
    __shared__ float s_Wout[256];
    __shared__ float s_Wsgp[256];
    __shared__ float s_agg[16*132];
    __shared__ float s_h[16*132];

    const int t  = threadIdx.x;
    const int nl = t >> 4;
    const int c  = t & 15;
    const int lane  = t & 63;
    const int gbase = lane & 48;       // channel-group base within wave
    const long long nodeBase = (long long)blockIdx.x * 16;
    const long long n = nodeBase + nl;

    s_wr[t]       = Wrbf[t];
    s_wr[t + 256] = Wrbf[t + 256];
    s_Wout[t] = Wout[t];
    s_Wsgp[t] = Wsgp[t];

    for (int idx = t; idx < 512; idx += 256) {
        int nn = idx >> 5;
        int r  = idx & 31;
        long long node = nodeBase + nn;
        float4 vh = make_float4(0,0,0,0);
        if (node < N) vh = *(const float4*)(h + node*128 + (long long)r*4);
        *(float4*)(&s_h[nn*132 + r*4]) = vh;
    }
    __syncthreads();

    float m0=0,m1=0,m2=0,m3=0,m4=0,m5=0,m6=0,m7=0;
    if (n < N) {
        const int start = (int)n * MAXDEG;
        const int dg    = min(deg[n], MAXDEG);
        const int dgE   = dg & ~1;

        for (int base = 0; base < dgE; base += 2) {
            const int2 ss  = *(const int2*)(rec + start + base);   // 2 srcs, one 8B load
            const float4 g0 = edata[start + base];
            const float4 g1 = edata[start + base + 1];

            // hoist h loads: 2 independent 32B chains in flight during w math
            const float4* hp0 = (const float4*)(h + (((long long)ss.x*16 + c) << 3));
            const float4* hp1 = (const float4*)(h + (((long long)ss.y*16 + c) << 3));
            const float4 A0 = hp0[0], B0 = hp0[1];
            const float4 A1 = hp1[0], B1 = hp1[1];

            // 5-term RBF window, clamped so kl+4 <= 31
            const int kl0 = min(max(0, __float2int_rn(g0.w * INV_MU) - 2), 27);
            const int kl1 = min(max(0, __float2int_rn(g1.w * INV_MU) - 2), 27);

            // cooperative exp: lanes 0-7 of the group cover edge0's window,
            // lanes 8-15 cover edge1's (lanes j>=5 of each half unused).
            const int   sel   = c >> 3;
            const float dsel  = sel ? g1.w : g0.w;
            const int   klsel = sel ? kl1 : kl0;
            const float xx = dsel - MU_STEP * (float)(klsel + (c & 7));
            const float ee = __expf(-GAMMA * xx * xx);

            float w0 = 0.0f, w1 = 0.0f;
            #pragma unroll
            for (int j = 0; j < 5; ++j) {
                const float e0 = __shfl(ee, gbase + j);
                const float e1 = __shfl(ee, gbase + 8 + j);
                w0 += e0 * s_wr[(kl0 + j)*16 + c];
                w1 += e1 * s_wr[(kl1 + j)*16 + c];
            }

            // gp(a, v), v grade-1 (= unit rel * env);
            // blades: 0:1 1:e1 2:e2 3:e3 4:e12 5:e13 6:e23 7:e123
            m0 += (A0.y*g0.x + A0.z*g0.y + A0.w*g0.z)*w0 + (A1.y*g1.x + A1.z*g1.y + A1.w*g1.z)*w1;
            m1 += (A0.x*g0.x + B0.x*g0.y + B0.y*g0.z)*w0 + (A1.x*g1.x + B1.x*g1.y + B1.y*g1.z)*w1;
            m2 += (A0.x*g0.y - B0.x*g0.x + B0.z*g0.z)*w0 + (A1.x*g1.y - B1.x*g1.x + B1.z*g1.z)*w1;
            m3 += (A0.x*g0.z - B0.y*g0.x - B0.z*g0.y)*w0 + (A1.x*g1.z - B1.y*g1.x - B1.z*g1.y)*w1;
            m4 += (A0.y*g0.y - A0.z*g0.x + B0.w*g0.z)*w0 + (A1.y*g1.y - A1.z*g1.x + B1.w*g1.z)*w1;
            m5 += (A0.y*g0.z - A0.w*g0.x - B0.w*g0.y)*w0 + (A1.y*g1.z - A1.w*g1.x - B1.w*g1.y)*w1;
            m6 += (A0.z*g0.z - A0.w*g0.y + B0.w*g0.x)*w0 + (A1.z*g1.z - A1.w*g1.y + B1.w*g1.x)*w1;
            m7 += (B0.z*g0.x - B0.y*g0.y + B0.x*g0.z)*w0 + (B1.z*g1.x - B1.y*g1.y + B1.x*g1.z)*w1;
        }

        if (dg & 1) {                          // peeled odd tail: single edge
            const int s0 = rec[start + dgE];
            const float4 g0 = edata[start + dgE];
            const float4* hp0 = (const float4*)(h + (((long long)s0*16 + c) << 3));
            const float4 A0 = hp0[0], B0 = hp0[1];

            const int kl0 = min(max(0, __float2int_rn(g0.w * INV_MU) - 2), 27);
            const float xx = g0.w - MU_STEP * (float)(kl0 + (c & 7));
            const float ee = __expf(-GAMMA * xx * xx);

            float w0 = 0.0f;
            #pragma unroll
            for (int j = 0; j < 5; ++j)
                w0 += __shfl(ee, gbase + j) * s_wr[(kl0 + j)*16 + c];

            m0 += (A0.y*g0.x + A0.z*g0.y + A0.w*g0.z)*w0;
            m1 += (A0.x*g0.x + B0.x*g0.y + B0.y*g0.z)*w0;
            m2 += (A0.x*g0.y - B0.x*g0.x + B0.z*g0.z)*w0;
            m3 += (A0.x*g0.z - B0.y*g0.x - B0.z*g0.y)*w0;
            m4 += (A0.y*g0.y - A0.z*g0.x + B0.w*g0.z)*w0;
            m5 += (A0.y*g0.z - A0.w*g0.x - B0.w*g0.y)*w0;
            m6 += (A0.z*g0.z - A0.w*g0.y + B0.w*g0.x)*w0;
            m7 += (B0.z*g0.x - B0.y*g0.y + B0.x*g0.z)*w0;
        }
    }

    __syncthreads();
    float* ag = &s_agg[nl*132 + c*8];
    *(float4*)(ag)     = make_float4(m0, m1, m2, m3);
    *(float4*)(ag + 4) = make_float4(m4, m5, m6, m7);
    __syncthreads();

    const int o = c;
    const float* A = &s_agg[nl*132];
    const float* H = &s_h[nl*132];

    float o0=0,o1=0,o2=0,o3=0,o4=0,o5=0,o6=0,o7=0;
    float q0=0,q1=0,q2=0,q3=0,q4=0,q5=0,q6=0,q7=0;
    #pragma unroll
    for (int cc = 0; cc < 16; ++cc) {
        const float wo = s_Wout[cc*16 + o];
        const float ws = s_Wsgp[cc*16 + o];
        const float* a  = A + cc*8;
        const float* hh = H + cc*8;
        o0 += a[0]*wo; o1 += a[1]*wo; o2 += a[2]*wo; o3 += a[3]*wo;
        o4 += a[4]*wo; o5 += a[5]*wo; o6 += a[6]*wo; o7 += a[7]*wo;
        q0 += hh[0]*ws; q1 += hh[1]*ws; q2 += hh[2]*ws; q3 += hh[3]*ws;
        q4 += hh[4]*ws; q5 += hh[5]*ws; q6 += hh[6]*ws; q7 += hh[7]*ws;
    }

    // res = out + gp(out, q), full Cl(3,0) Cayley product
    const float r0 = o0 + (o0*q0 + o1*q1 + o2*q2 + o3*q3 - o4*q4 - o5*q5 - o6*q6 - o7*q7);
    const float r1 = o1 + (o0*q1 + o1*q0 - o2*q4 - o3*q5 + o4*q2 + o5*q3 - o6*q7 - o7*q6);
    const float r2 = o2 + (o0*q2 + o1*q4 + o2*q0 - o3*q6 - o4*q1 + o5*q7 + o6*q3 + o7*q5);
    const float r3 = o3 + (o0*q3 + o1*q5 + o2*q6 + o3*q0 - o4*q7 - o5*q1 - o6*q2 - o7*q4);
    const float r4 = o4 + (o0*q4 + o1*q2 - o2*q1 + o3*q7 + o4*q0 - o5*q6 + o6*q5 + o7*q3);
    const float r5 = o5 + (o0*q5 + o1*q3 - o2*q7 - o3*q1 + o4*q6 + o5*q0 - o6*q4 - o7*q2);
    const float r6 = o6 + (o0*q6 + o1*q7 + o2*q3 - o3*q2 - o4*q5 + o5*q4 + o6*q0 + o7*q1);
    const float r7 = o7 + (o0*q7 + o1*q6 - o2*q5 + o3*q4 + o4*q3 - o5*q2 + o6*q1 + o7*q0);

    if (n < N) {
        float* op = out + (n*16 + o)*8;
        *(float4*)(op)     = make_float4(r0, r1, r2, r3);
        *(float4*)(op + 4) = make_float4(r4, r5, r6, r7);
    }
}

extern "C" void kernel_launch(void* const* d_in, const int* in_sizes, int n_in,
                              void* d_out, int out_size, void* d_ws, size_t ws_size,
                              hipStream_t stream) {
    const float* h    = (const float*)d_in[0];   // [N,16,8]
    const float* pos  = (const float*)d_in[1];   // [N,3]
    const int*   ei   = (const int*)d_in[2];     // [2,E]
    const float* Wrbf = (const float*)d_in[3];   // [32,16]
    const float* Wout = (const float*)d_in[4];   // [16,16]
    const float* Wsgp = (const float*)d_in[5];   // [16,16]
    float* out = (float*)d_out;

    const int N = in_sizes[0] / 128;
    const int E = in_sizes[2] / 2;

    // ws layout: edata float4[N*MAXDEG] (19.2MB) | deg[N] | rec[N*MAXDEG] (4.8MB)
    float4* edata = (float4*)d_ws;
    int* deg = (int*)(edata + (size_t)N * MAXDEG);
    int* rec = deg + N;

    hipMemsetAsync(deg, 0, (size_t)N * sizeof(int), stream);

    const int eBlocks = (E + 255) / 256;
    k_fill_geom<<<eBlocks, 256, 0, stream>>>(pos, ei, deg, rec, edata, E);

    const int gBlocks = (N + 15) / 16;
    k_gather_finalize<<<gBlocks, 256, 0, stream>>>(
        h, rec, deg, edata, Wrbf, Wout, Wsgp, out, N);
}